// Round 1
// baseline (677.462 us; speedup 1.0000x reference)
//
#include <hip/hip_runtime.h>
#include <hip/hip_bf16.h>
#include <math.h>

// Problem constants (FusedRoutedMLP)
#define E    8
#define H    1024
#define I2   2816          // 2*I
#define II   1408          // I
#define T    2048
#define KTOP 2
#define NP   (T * KTOP)    // 4096 (token, expert-slot) pairs

// Tiling
#define BM 64
#define BN 64
#define BK 32
#define MAXT (NP / BM + E - 1)   // 71: worst-case total row tiles across experts

// ---------------------------------------------------------------------------
// Routing: counting sort of 4096 pairs into expert-contiguous segments.
// Single block, 256 threads.
// ---------------------------------------------------------------------------
__global__ void route_kernel(const int* __restrict__ ids, const float* __restrict__ rw,
                             int* __restrict__ tok, float* __restrict__ wt,
                             int* __restrict__ seg_off, int* __restrict__ tile_off)
{
    __shared__ int cnt[E];
    __shared__ int base[E + 1];
    __shared__ int pos[E];
    int tid = threadIdx.x;
    if (tid < E) { cnt[tid] = 0; pos[tid] = 0; }
    __syncthreads();
    for (int p = tid; p < NP; p += blockDim.x) atomicAdd(&cnt[ids[p]], 1);
    __syncthreads();
    if (tid == 0) {
        int s = 0;
        for (int e = 0; e < E; ++e) { base[e] = s; s += cnt[e]; }
        base[E] = s;
    }
    __syncthreads();
    for (int p = tid; p < NP; p += blockDim.x) {
        int e = ids[p];
        int q = base[e] + atomicAdd(&pos[e], 1);
        tok[q] = p >> 1;      // token index (K=2)
        wt[q]  = rw[p];
    }
    if (tid == 0) {
        int s = 0;
        for (int e = 0; e < E; ++e) {
            seg_off[e]  = base[e];
            tile_off[e] = s;
            s += (cnt[e] + BM - 1) / BM;
        }
        seg_off[E]  = base[E];
        tile_off[E] = s;
    }
}

// ---------------------------------------------------------------------------
// GEMM1 + SiLU: act[p, j] = silu(x[tok[p]] . w1[e][:, j]) * (x[tok[p]] . w1[e][:, I+j])
// Block: 64 pair-rows x 64 act-cols, K over H. 256 threads, 4x4 microtile.
// ---------------------------------------------------------------------------
__launch_bounds__(256)
__global__ void gemm1_silu(const float* __restrict__ x, const float* __restrict__ w1,
                           const int* __restrict__ tok, const int* __restrict__ seg_off,
                           const int* __restrict__ tile_off, float* __restrict__ act)
{
    __shared__ float As[BK][BM + 4];   // transposed: As[kk][row]
    __shared__ float Bg[BK][BN + 4];
    __shared__ float Bu[BK][BN + 4];
    __shared__ int   tokS[BM];

    int bx = blockIdx.x;
    if (bx >= tile_off[E]) return;
    int e = 0;
#pragma unroll
    for (int i = 1; i < E; ++i) if (bx >= tile_off[i]) e = i;
    int row0 = seg_off[e] + (bx - tile_off[e]) * BM;
    int rend = seg_off[e + 1];
    int jb   = blockIdx.y * BN;

    int tid = threadIdx.x;
    if (tid < BM) {
        int gr = row0 + tid;
        tokS[tid] = tok[gr < NP ? gr : NP - 1];
    }
    __syncthreads();

    float accg[4][4] = {};
    float accu[4][4] = {};
    const int r0 = (tid >> 4) * 4;     // 4 rows
    const int c0 = (tid & 15) * 4;     // 4 cols (consecutive tids -> consecutive cols)
    const int ar = tid >> 3;           // A-load: row 0..31 (+32)
    const int ac = (tid & 7) * 4;      // A-load col
    const int br = tid >> 4;           // B-load: row 0..15 (+16)
    const int bc = (tid & 15) * 4;     // B-load col

    const float* w1e = w1 + (size_t)e * H * I2;

    for (int k0 = 0; k0 < H; k0 += BK) {
#pragma unroll
        for (int t = 0; t < 2; ++t) {
            int r = ar + t * 32;
            int tokr = tokS[r];
            float4 v = *(const float4*)(x + (size_t)tokr * H + k0 + ac);
            As[ac + 0][r] = v.x; As[ac + 1][r] = v.y;
            As[ac + 2][r] = v.z; As[ac + 3][r] = v.w;
        }
#pragma unroll
        for (int t = 0; t < 2; ++t) {
            int r = br + t * 16;
            const float* src = w1e + (size_t)(k0 + r) * I2 + jb + bc;
            *(float4*)&Bg[r][bc] = *(const float4*)(src);
            *(float4*)&Bu[r][bc] = *(const float4*)(src + II);
        }
        __syncthreads();
#pragma unroll
        for (int kk = 0; kk < BK; ++kk) {
            float4 a4 = *(const float4*)&As[kk][r0];
            float4 g4 = *(const float4*)&Bg[kk][c0];
            float4 u4 = *(const float4*)&Bu[kk][c0];
            float av[4] = {a4.x, a4.y, a4.z, a4.w};
            float gv[4] = {g4.x, g4.y, g4.z, g4.w};
            float uv[4] = {u4.x, u4.y, u4.z, u4.w};
#pragma unroll
            for (int i = 0; i < 4; ++i)
#pragma unroll
                for (int j = 0; j < 4; ++j) {
                    accg[i][j] += av[i] * gv[j];
                    accu[i][j] += av[i] * uv[j];
                }
        }
        __syncthreads();
    }

#pragma unroll
    for (int i = 0; i < 4; ++i) {
        int gr = row0 + r0 + i;
        if (gr < rend) {
            float4 o;
            float* op = (float*)&o;
#pragma unroll
            for (int j = 0; j < 4; ++j) {
                float g = accg[i][j];
                float s = g / (1.0f + __expf(-g));   // silu
                op[j] = s * accu[i][j];
            }
            *(float4*)(act + (size_t)gr * II + jb + c0) = o;
        }
    }
}

// ---------------------------------------------------------------------------
// GEMM2 + weighted scatter: out[tok[p]] += wt[p] * (act[p] . w2[e])
// ---------------------------------------------------------------------------
__launch_bounds__(256)
__global__ void gemm2_scatter(const float* __restrict__ act, const float* __restrict__ w2,
                              const int* __restrict__ tok, const float* __restrict__ wt,
                              const int* __restrict__ seg_off, const int* __restrict__ tile_off,
                              float* __restrict__ out)
{
    __shared__ float As[BK][BM + 4];
    __shared__ float Bs[BK][BN + 4];
    __shared__ int   tokS[BM];
    __shared__ float wtS[BM];

    int bx = blockIdx.x;
    if (bx >= tile_off[E]) return;
    int e = 0;
#pragma unroll
    for (int i = 1; i < E; ++i) if (bx >= tile_off[i]) e = i;
    int row0 = seg_off[e] + (bx - tile_off[e]) * BM;
    int rend = seg_off[e + 1];
    int jb   = blockIdx.y * BN;

    int tid = threadIdx.x;
    if (tid < BM) {
        int gr = row0 + tid; gr = gr < NP ? gr : NP - 1;
        tokS[tid] = tok[gr];
        wtS[tid]  = wt[gr];
    }
    __syncthreads();

    float acc[4][4] = {};
    const int r0 = (tid >> 4) * 4;
    const int c0 = (tid & 15) * 4;
    const int ar = tid >> 3;
    const int ac = (tid & 7) * 4;
    const int br = tid >> 4;
    const int bc = (tid & 15) * 4;

    const float* w2e = w2 + (size_t)e * II * H;

    for (int k0 = 0; k0 < II; k0 += BK) {
#pragma unroll
        for (int t = 0; t < 2; ++t) {
            int r = ar + t * 32;
            int gr = row0 + r; gr = gr < NP ? gr : NP - 1;
            float4 v = *(const float4*)(act + (size_t)gr * II + k0 + ac);
            As[ac + 0][r] = v.x; As[ac + 1][r] = v.y;
            As[ac + 2][r] = v.z; As[ac + 3][r] = v.w;
        }
#pragma unroll
        for (int t = 0; t < 2; ++t) {
            int r = br + t * 16;
            *(float4*)&Bs[r][bc] = *(const float4*)(w2e + (size_t)(k0 + r) * H + jb + bc);
        }
        __syncthreads();
#pragma unroll
        for (int kk = 0; kk < BK; ++kk) {
            float4 a4 = *(const float4*)&As[kk][r0];
            float4 b4 = *(const float4*)&Bs[kk][c0];
            float av[4] = {a4.x, a4.y, a4.z, a4.w};
            float bv[4] = {b4.x, b4.y, b4.z, b4.w};
#pragma unroll
            for (int i = 0; i < 4; ++i)
#pragma unroll
                for (int j = 0; j < 4; ++j)
                    acc[i][j] += av[i] * bv[j];
        }
        __syncthreads();
    }

#pragma unroll
    for (int i = 0; i < 4; ++i) {
        int lr = r0 + i;
        int gr = row0 + lr;
        if (gr < rend) {
            int   t = tokS[lr];
            float w = wtS[lr];
            float* dst = out + (size_t)t * H + jb + c0;
#pragma unroll
            for (int j = 0; j < 4; ++j) atomicAdd(dst + j, w * acc[i][j]);
        }
    }
}

// ---------------------------------------------------------------------------
extern "C" void kernel_launch(void* const* d_in, const int* in_sizes, int n_in,
                              void* d_out, int out_size, void* d_ws, size_t ws_size,
                              hipStream_t stream)
{
    const float* x   = (const float*)d_in[0];
    const int*   ids = (const int*)d_in[1];
    const float* rw  = (const float*)d_in[2];
    const float* w1  = (const float*)d_in[3];
    const float* w2  = (const float*)d_in[4];
    float*       out = (float*)d_out;

    char* ws = (char*)d_ws;
    int*   tok  = (int*)ws;                          // 4096 ints
    float* wt   = (float*)(ws + 4096 * 4);           // 4096 floats
    int*   seg  = (int*)(ws + 8192 * 4);             // E+1 ints
    int*   tile = (int*)(ws + (8192 + 16) * 4);      // E+1 ints
    float* act  = (float*)(ws + 65536);              // 4096 x 1408 floats (~23 MB)

    hipMemsetAsync(d_out, 0, (size_t)out_size * sizeof(float), stream);

    route_kernel<<<1, 256, 0, stream>>>(ids, rw, tok, wt, seg, tile);

    dim3 g1(MAXT, II / BN);   // (71, 22)
    gemm1_silu<<<g1, 256, 0, stream>>>(x, w1, tok, seg, tile, act);

    dim3 g2(MAXT, H / BN);    // (71, 16)
    gemm2_scatter<<<g2, 256, 0, stream>>>(act, w2, tok, wt, seg, tile, out);
}

// Round 4
// 303.398 us; speedup vs baseline: 2.2329x; 2.2329x over previous
//
#include <hip/hip_runtime.h>
#include <hip/hip_bf16.h>
#include <math.h>

// Problem constants (FusedRoutedMLP)
#define E    8
#define H    1024
#define I2   2816          // 2*I
#define II   1408          // I
#define T    2048
#define KTOP 2
#define NP   (T * KTOP)    // 4096 (token, expert-slot) pairs

// GEMM tiling
#define BM   128           // pair-rows per block (both GEMMs)
#define BK   32            // bf16 K-step (one 16x16x32 MFMA K)
#define BNA  64            // act cols per gemm1 block (=> 128 B-cols: gate+up)
#define BN2  128           // out cols per gemm2 block
#define GX   40            // grid.x upper bound: 4096/128 + 8

typedef __attribute__((ext_vector_type(8))) short  short8v;   // 8 bf16 = 4 VGPR
typedef __attribute__((ext_vector_type(4))) float  f32x4;
typedef __attribute__((ext_vector_type(8))) unsigned short ushort8;

__device__ __forceinline__ void gload16(void* lds, const void* g) {
    // async global->LDS, 16B per lane; LDS dest = wave-uniform base + lane*16
    __builtin_amdgcn_global_load_lds((const __attribute__((address_space(1))) unsigned int*)g,
                                     (__attribute__((address_space(3))) unsigned int*)lds,
                                     16, 0, 0);
}

// ---------------------------------------------------------------------------
// Routing: counting sort of 4096 pairs into expert-contiguous segments.
// ---------------------------------------------------------------------------
__global__ void route_kernel(const int* __restrict__ ids, const float* __restrict__ rw,
                             int* __restrict__ tok, float* __restrict__ wt,
                             int* __restrict__ seg_off, int* __restrict__ tile_off)
{
    __shared__ int cnt[E];
    __shared__ int base[E + 1];
    __shared__ int pos[E];
    int tid = threadIdx.x;
    if (tid < E) { cnt[tid] = 0; pos[tid] = 0; }
    __syncthreads();
    for (int p = tid; p < NP; p += blockDim.x) atomicAdd(&cnt[ids[p]], 1);
    __syncthreads();
    if (tid == 0) {
        int s = 0;
        for (int e = 0; e < E; ++e) { base[e] = s; s += cnt[e]; }
        base[E] = s;
    }
    __syncthreads();
    for (int p = tid; p < NP; p += blockDim.x) {
        int e = ids[p];
        int q = base[e] + atomicAdd(&pos[e], 1);
        tok[q] = p >> 1;      // token index (K=2)
        wt[q]  = rw[p];
    }
    if (tid == 0) {
        int s = 0;
        for (int e = 0; e < E; ++e) {
            seg_off[e]  = base[e];
            tile_off[e] = s;
            s += (cnt[e] + BM - 1) / BM;
        }
        seg_off[E]  = base[E];
        tile_off[E] = s;
    }
}

// ---------------------------------------------------------------------------
// x fp32 -> bf16 (same layout)
// ---------------------------------------------------------------------------
__global__ void cvt_x(const float* __restrict__ src, __hip_bfloat16* __restrict__ dst, int n)
{
    int i = (blockIdx.x * blockDim.x + threadIdx.x) * 8;
    if (i >= n) return;
    float4 a = *(const float4*)(src + i);
    float4 b = *(const float4*)(src + i + 4);
    alignas(16) __hip_bfloat16 t[8];
    t[0] = __float2bfloat16(a.x); t[1] = __float2bfloat16(a.y);
    t[2] = __float2bfloat16(a.z); t[3] = __float2bfloat16(a.w);
    t[4] = __float2bfloat16(b.x); t[5] = __float2bfloat16(b.y);
    t[6] = __float2bfloat16(b.z); t[7] = __float2bfloat16(b.w);
    *(ushort8*)(dst + i) = *(ushort8*)t;
}

// ---------------------------------------------------------------------------
// Weight transpose+convert: src [e][K][N] fp32  ->  dst [e][N][K] bf16
// 64x64 tiles, coalesced read & write, padded LDS (conflict-free).
// ---------------------------------------------------------------------------
__launch_bounds__(256)
__global__ void transpose_cvt(const float* __restrict__ src, __hip_bfloat16* __restrict__ dst,
                              int K, int N)
{
    __shared__ float tile[64][65];
    int e  = blockIdx.z;
    int n0 = blockIdx.x * 64;
    int k0 = blockIdx.y * 64;
    int tid = threadIdx.x;

    const float* s = src + (size_t)e * K * N + (size_t)k0 * N + n0;
    int kr = tid >> 2;
    int nc = (tid & 3) * 16;
    const float* srow = s + (size_t)kr * N + nc;
#pragma unroll
    for (int i = 0; i < 4; ++i) {
        float4 v = *(const float4*)(srow + i * 4);
        tile[kr][nc + i * 4 + 0] = v.x;
        tile[kr][nc + i * 4 + 1] = v.y;
        tile[kr][nc + i * 4 + 2] = v.z;
        tile[kr][nc + i * 4 + 3] = v.w;
    }
    __syncthreads();
    int nr = tid >> 2;
    int kc = (tid & 3) * 16;
    alignas(16) __hip_bfloat16 tmp[16];
#pragma unroll
    for (int i = 0; i < 16; ++i) tmp[i] = __float2bfloat16(tile[kc + i][nr]);
    __hip_bfloat16* drow = dst + (size_t)e * K * N + (size_t)(n0 + nr) * K + k0 + kc;
    *(ushort8*)(drow)     = *(ushort8*)tmp;
    *(ushort8*)(drow + 8) = *(ushort8*)(tmp + 8);
}

// ---------------------------------------------------------------------------
// GEMM1 + SiLU (bf16 MFMA): act[p, 0:64@jb] = silu(x.w1g) * (x.w1u)
// Tile: 128 rows x 64 act-cols (=> gate 64 + up 64 B-cols), 4 waves 2x2.
// ---------------------------------------------------------------------------
__launch_bounds__(256, 2)
__global__ void gemm1_silu(const __hip_bfloat16* __restrict__ xb,
                           const __hip_bfloat16* __restrict__ w1t,   // [e][n=2816][k=1024]
                           const int* __restrict__ tok,
                           const int* __restrict__ seg_off,
                           const int* __restrict__ tile_off,
                           __hip_bfloat16* __restrict__ act)         // [p][1408]
{
    __shared__ __align__(16) __hip_bfloat16 As[BM * BK];    // [row][k] 8KB
    __shared__ __align__(16) __hip_bfloat16 Bg[BNA * BK];   // [col][k] 4KB
    __shared__ __align__(16) __hip_bfloat16 Bu[BNA * BK];   // 4KB
    __shared__ int tokS[BM];

    int bx = blockIdx.x;
    if (bx >= tile_off[E]) return;
    int e = 0;
#pragma unroll
    for (int i = 1; i < E; ++i) if (bx >= tile_off[i]) e = i;
    int row0 = seg_off[e] + (bx - tile_off[e]) * BM;
    int rend = seg_off[e + 1];
    int jb   = blockIdx.y * BNA;

    int tid = threadIdx.x;
    if (tid < BM) {
        int gr = row0 + tid;
        tokS[tid] = tok[gr < NP ? gr : NP - 1];
    }
    __syncthreads();

    // staging addresses: thread covers 16B; row = tid/4, byte-in-row = (tid&3)*16
    int arow = tid >> 2;
    int aoff = (tid & 3) * 16;
    const char* xB  = (const char*)xb;
    const char* w1B = (const char*)(w1t + (size_t)e * I2 * H);
    const char* srcA0 = xB + (size_t)tokS[arow]      * 2048 + aoff;   // rows 0..63
    const char* srcA1 = xB + (size_t)tokS[arow + 64] * 2048 + aoff;   // rows 64..127
    const char* srcG  = w1B + (size_t)(jb + arow)      * 2048 + aoff;
    const char* srcU  = w1B + (size_t)(II + jb + arow) * 2048 + aoff;
    __hip_bfloat16* dA0 = &As[tid * 8];
    __hip_bfloat16* dA1 = &As[2048 + tid * 8];
    __hip_bfloat16* dG  = &Bg[tid * 8];
    __hip_bfloat16* dU  = &Bu[tid * 8];

    int lane = tid & 63;
    int w  = tid >> 6;
    int wm = w >> 1, wn = w & 1;   // wave region: rows wm*64, act-cols wn*32
    int fr = lane & 15;            // fragment row/col
    int kc = lane >> 4;            // k-chunk (8 elems each)

    f32x4 accg[4][2] = {};
    f32x4 accu[4][2] = {};
    const short8v* Asv = (const short8v*)As;
    const short8v* Bgv = (const short8v*)Bg;
    const short8v* Buv = (const short8v*)Bu;

    for (int k0 = 0; k0 < H; k0 += BK) {
        gload16(dA0, srcA0);
        gload16(dA1, srcA1);
        gload16(dG, srcG);
        gload16(dU, srcU);
        srcA0 += 64; srcA1 += 64; srcG += 64; srcU += 64;
        __syncthreads();   // drains vmcnt before LDS reads

        short8v a[4], g[2], u[2];
#pragma unroll
        for (int m = 0; m < 4; ++m)
            a[m] = Asv[(wm * 64 + m * 16 + fr) * 4 + kc];
#pragma unroll
        for (int n = 0; n < 2; ++n) {
            g[n] = Bgv[(wn * 32 + n * 16 + fr) * 4 + kc];
            u[n] = Buv[(wn * 32 + n * 16 + fr) * 4 + kc];
        }
#pragma unroll
        for (int m = 0; m < 4; ++m)
#pragma unroll
            for (int n = 0; n < 2; ++n) {
                accg[m][n] = __builtin_amdgcn_mfma_f32_16x16x32_bf16(a[m], g[n], accg[m][n], 0, 0, 0);
                accu[m][n] = __builtin_amdgcn_mfma_f32_16x16x32_bf16(a[m], u[n], accu[m][n], 0, 0, 0);
            }
        __syncthreads();
    }

    // epilogue: silu(gate)*up -> bf16 act.  C/D layout: col=lane&15, row=(lane>>4)*4+j
#pragma unroll
    for (int m = 0; m < 4; ++m)
#pragma unroll
        for (int n = 0; n < 2; ++n) {
            int col = jb + wn * 32 + n * 16 + fr;
#pragma unroll
            for (int j = 0; j < 4; ++j) {
                int gr = row0 + wm * 64 + m * 16 + kc * 4 + j;
                if (gr < rend) {
                    float gg = accg[m][n][j];
                    float s  = gg / (1.0f + __expf(-gg));
                    act[(size_t)gr * II + col] = __float2bfloat16(s * accu[m][n][j]);
                }
            }
        }
}

// ---------------------------------------------------------------------------
// GEMM2 + weighted scatter: out[tok[p]] += wt[p] * (act[p] . w2[e])
// Tile: 128 rows x 128 cols, 4 waves 2x2, K=1408.
// ---------------------------------------------------------------------------
__launch_bounds__(256, 2)
__global__ void gemm2_scatter(const __hip_bfloat16* __restrict__ act,
                              const __hip_bfloat16* __restrict__ w2t,  // [e][n=1024][k=1408]
                              const int* __restrict__ tok,
                              const float* __restrict__ wt,
                              const int* __restrict__ seg_off,
                              const int* __restrict__ tile_off,
                              float* __restrict__ out)
{
    __shared__ __align__(16) __hip_bfloat16 As[BM * BK];     // 8KB
    __shared__ __align__(16) __hip_bfloat16 Bs[BN2 * BK];    // 8KB
    __shared__ int   tokS[BM];
    __shared__ float wtS[BM];

    int bx = blockIdx.x;
    if (bx >= tile_off[E]) return;
    int e = 0;
#pragma unroll
    for (int i = 1; i < E; ++i) if (bx >= tile_off[i]) e = i;
    int row0 = seg_off[e] + (bx - tile_off[e]) * BM;
    int rend = seg_off[e + 1];
    int nb   = blockIdx.y * BN2;

    int tid = threadIdx.x;
    if (tid < BM) {
        int gr = row0 + tid; gr = gr < NP ? gr : NP - 1;
        tokS[tid] = tok[gr];
        wtS[tid]  = wt[gr];
    }
    __syncthreads();

    int arow = tid >> 2;
    int aoff = (tid & 3) * 16;
    const char* actB = (const char*)act;
    const char* w2B  = (const char*)(w2t + (size_t)e * H * II);
    int r0c = row0 + arow;       r0c = r0c < NP ? r0c : NP - 1;
    int r1c = row0 + arow + 64;  r1c = r1c < NP ? r1c : NP - 1;
    const char* srcA0 = actB + (size_t)r0c * 2816 + aoff;
    const char* srcA1 = actB + (size_t)r1c * 2816 + aoff;
    const char* srcB0 = w2B + (size_t)(nb + arow)      * 2816 + aoff;
    const char* srcB1 = w2B + (size_t)(nb + arow + 64) * 2816 + aoff;
    __hip_bfloat16* dA0 = &As[tid * 8];
    __hip_bfloat16* dA1 = &As[2048 + tid * 8];
    __hip_bfloat16* dB0 = &Bs[tid * 8];
    __hip_bfloat16* dB1 = &Bs[2048 + tid * 8];

    int lane = tid & 63;
    int w  = tid >> 6;
    int wm = w >> 1, wn = w & 1;   // wave region: rows wm*64, cols wn*64
    int fr = lane & 15;
    int kc = lane >> 4;

    f32x4 acc[4][4] = {};
    const short8v* Asv = (const short8v*)As;
    const short8v* Bsv = (const short8v*)Bs;

    for (int k0 = 0; k0 < II; k0 += BK) {
        gload16(dA0, srcA0);
        gload16(dA1, srcA1);
        gload16(dB0, srcB0);
        gload16(dB1, srcB1);
        srcA0 += 64; srcA1 += 64; srcB0 += 64; srcB1 += 64;
        __syncthreads();

        short8v a[4], b[4];
#pragma unroll
        for (int m = 0; m < 4; ++m)
            a[m] = Asv[(wm * 64 + m * 16 + fr) * 4 + kc];
#pragma unroll
        for (int n = 0; n < 4; ++n)
            b[n] = Bsv[(wn * 64 + n * 16 + fr) * 4 + kc];
#pragma unroll
        for (int m = 0; m < 4; ++m)
#pragma unroll
            for (int n = 0; n < 4; ++n)
                acc[m][n] = __builtin_amdgcn_mfma_f32_16x16x32_bf16(a[m], b[n], acc[m][n], 0, 0, 0);
        __syncthreads();
    }

#pragma unroll
    for (int m = 0; m < 4; ++m)
#pragma unroll
        for (int n = 0; n < 4; ++n) {
            int col = nb + wn * 64 + n * 16 + fr;
#pragma unroll
            for (int j = 0; j < 4; ++j) {
                int lr = wm * 64 + m * 16 + kc * 4 + j;
                int gr = row0 + lr;
                if (gr < rend)
                    atomicAdd(&out[(size_t)tokS[lr] * H + col], wtS[lr] * acc[m][n][j]);
            }
        }
}

// ---------------------------------------------------------------------------
extern "C" void kernel_launch(void* const* d_in, const int* in_sizes, int n_in,
                              void* d_out, int out_size, void* d_ws, size_t ws_size,
                              hipStream_t stream)
{
    const float* x   = (const float*)d_in[0];
    const int*   ids = (const int*)d_in[1];
    const float* rw  = (const float*)d_in[2];
    const float* w1  = (const float*)d_in[3];
    const float* w2  = (const float*)d_in[4];
    float*       out = (float*)d_out;

    char* ws = (char*)d_ws;
    int*   tok  = (int*)ws;                              // 16 KB
    float* wt   = (float*)(ws + 16384);                  // 16 KB
    int*   seg  = (int*)(ws + 32768);                    // E+1
    int*   tile = (int*)(ws + 32768 + 64);               // E+1
    __hip_bfloat16* xb  = (__hip_bfloat16*)(ws + 65536);                 // 4 MB
    __hip_bfloat16* w1t = (__hip_bfloat16*)(ws + 65536 + 4194304);       // 46.1 MB
    __hip_bfloat16* w2t = (__hip_bfloat16*)(ws + 65536 + 4194304 + 46137344);   // 23.1 MB
    __hip_bfloat16* act = (__hip_bfloat16*)(ws + 65536 + 4194304 + 46137344 + 23068672); // 11.5 MB

    hipMemsetAsync(d_out, 0, (size_t)out_size * sizeof(float), stream);

    cvt_x<<<(T * H) / (256 * 8), 256, 0, stream>>>(x, xb, T * H);
    transpose_cvt<<<dim3(I2 / 64, H / 64, E), 256, 0, stream>>>(w1, w1t, H, I2);   // (44,16,8)
    transpose_cvt<<<dim3(H / 64, II / 64, E), 256, 0, stream>>>(w2, w2t, II, H);   // (16,22,8)
    route_kernel<<<1, 256, 0, stream>>>(ids, rw, tok, wt, seg, tile);

    gemm1_silu<<<dim3(GX, II / BNA), 256, 0, stream>>>(xb, w1t, tok, seg, tile, act);      // (40,22)
    gemm2_scatter<<<dim3(GX, H / BN2), 256, 0, stream>>>(act, w2t, tok, wt, seg, tile, out); // (40,8)
}

// Round 5
// 277.979 us; speedup vs baseline: 2.4371x; 1.0914x over previous
//
#include <hip/hip_runtime.h>
#include <hip/hip_bf16.h>
#include <math.h>

// Problem constants (FusedRoutedMLP)
#define E    8
#define H    1024
#define I2   2816          // 2*I
#define II   1408          // I
#define T    2048
#define KTOP 2
#define NP   (T * KTOP)    // 4096 (token, expert-slot) pairs

// GEMM tiling
#define BM   128           // pair-rows per block (both GEMMs)
#define BK   32            // bf16 K-step (one 16x16x32 MFMA K)
#define BNA  64            // act cols per gemm1 block (=> 128 B-cols: gate+up)
#define BN2  128           // out cols per gemm2 block
#define GX   40            // grid.x upper bound: 4096/128 + 8

// prep kernel block ranges
#define CVT_BLKS   1024               // (T*H)/(256*8)
#define TW1_PER_E  (44 * 16)          // n-tiles x k-tiles for w1 (2816/64, 1024/64)
#define TW1_BLKS   (TW1_PER_E * E)    // 5632
#define TW2_PER_E  (16 * 22)          // n-tiles x k-tiles for w2 (1024/64, 1408/64)
#define TW2_BLKS   (TW2_PER_E * E)    // 2816
#define PREP_BLKS  (CVT_BLKS + TW1_BLKS + TW2_BLKS + 1)   // 9473 (last = route)

typedef __attribute__((ext_vector_type(8))) short  short8v;   // 8 bf16 = 4 VGPR
typedef __attribute__((ext_vector_type(4))) float  f32x4;
typedef __attribute__((ext_vector_type(8))) unsigned short ushort8;

__device__ __forceinline__ void gload16(void* lds, const void* g) {
    // async global->LDS, 16B per lane; LDS dest = wave-uniform base + lane*16
    __builtin_amdgcn_global_load_lds((const __attribute__((address_space(1))) unsigned int*)g,
                                     (__attribute__((address_space(3))) unsigned int*)lds,
                                     16, 0, 0);
}

union PrepShared {
    float tile[64][65];                                   // transpose staging (16.6 KB)
    struct { int cnt[E]; int base[E + 1]; int pos[E]; } rt;
};

// 64x64 transpose+convert tile: src [K][N] fp32 (expert e) -> dst [N][K] bf16
__device__ __forceinline__ void transpose_tile(const float* __restrict__ src,
                                               __hip_bfloat16* __restrict__ dst,
                                               int e, int n0, int k0, int K, int N,
                                               PrepShared& sh, int tid)
{
    const float* s = src + (size_t)e * K * N + (size_t)k0 * N + n0;
    int kr = tid >> 2;
    int nc = (tid & 3) * 16;
    const float* srow = s + (size_t)kr * N + nc;
#pragma unroll
    for (int i = 0; i < 4; ++i) {
        float4 v = *(const float4*)(srow + i * 4);
        sh.tile[kr][nc + i * 4 + 0] = v.x;
        sh.tile[kr][nc + i * 4 + 1] = v.y;
        sh.tile[kr][nc + i * 4 + 2] = v.z;
        sh.tile[kr][nc + i * 4 + 3] = v.w;
    }
    __syncthreads();
    int nr = tid >> 2;
    int kc = (tid & 3) * 16;
    alignas(16) __hip_bfloat16 tmp[16];
#pragma unroll
    for (int i = 0; i < 16; ++i) tmp[i] = __float2bfloat16(sh.tile[kc + i][nr]);
    __hip_bfloat16* drow = dst + (size_t)e * K * N + (size_t)(n0 + nr) * K + k0 + kc;
    *(ushort8*)(drow)     = *(ushort8*)tmp;
    *(ushort8*)(drow + 8) = *(ushort8*)(tmp + 8);
}

// ---------------------------------------------------------------------------
// prep: fused {x->bf16 convert | w1 transpose | w2 transpose | routing sort}
// ---------------------------------------------------------------------------
__launch_bounds__(256)
__global__ void prep_kernel(const float* __restrict__ x, const float* __restrict__ w1,
                            const float* __restrict__ w2, const int* __restrict__ ids,
                            __hip_bfloat16* __restrict__ xb,
                            __hip_bfloat16* __restrict__ w1t,
                            __hip_bfloat16* __restrict__ w2t,
                            int* __restrict__ tok, int* __restrict__ inv,
                            int* __restrict__ seg_off, int* __restrict__ tile_off)
{
    __shared__ PrepShared sh;
    int tid = threadIdx.x;
    int b = blockIdx.x;

    if (b < CVT_BLKS) {
        // x fp32 -> bf16, 8 elems/thread
        int i = (b * 256 + tid) * 8;
        float4 a = *(const float4*)(x + i);
        float4 c = *(const float4*)(x + i + 4);
        alignas(16) __hip_bfloat16 t[8];
        t[0] = __float2bfloat16(a.x); t[1] = __float2bfloat16(a.y);
        t[2] = __float2bfloat16(a.z); t[3] = __float2bfloat16(a.w);
        t[4] = __float2bfloat16(c.x); t[5] = __float2bfloat16(c.y);
        t[6] = __float2bfloat16(c.z); t[7] = __float2bfloat16(c.w);
        *(ushort8*)(xb + i) = *(ushort8*)t;
        return;
    }
    b -= CVT_BLKS;
    if (b < TW1_BLKS) {
        int e = b / TW1_PER_E, r = b % TW1_PER_E;
        transpose_tile(w1, w1t, e, (r % 44) * 64, (r / 44) * 64, H, I2, sh, tid);
        return;
    }
    b -= TW1_BLKS;
    if (b < TW2_BLKS) {
        int e = b / TW2_PER_E, r = b % TW2_PER_E;
        transpose_tile(w2, w2t, e, (r % 16) * 64, (r / 16) * 64, II, H, sh, tid);
        return;
    }

    // routing: counting sort of 4096 pairs into expert-contiguous segments
    if (tid < E) { sh.rt.cnt[tid] = 0; sh.rt.pos[tid] = 0; }
    __syncthreads();
    for (int p = tid; p < NP; p += 256) atomicAdd(&sh.rt.cnt[ids[p]], 1);
    __syncthreads();
    if (tid == 0) {
        int s = 0;
        for (int e = 0; e < E; ++e) { sh.rt.base[e] = s; s += sh.rt.cnt[e]; }
        sh.rt.base[E] = s;
    }
    __syncthreads();
    for (int p = tid; p < NP; p += 256) {
        int e = ids[p];
        int q = sh.rt.base[e] + atomicAdd(&sh.rt.pos[e], 1);
        tok[q] = p >> 1;      // token index (K=2)
        inv[p] = q;           // inverse permutation for the final gather
    }
    if (tid == 0) {
        int s = 0;
        for (int e = 0; e < E; ++e) {
            seg_off[e]  = sh.rt.base[e];
            tile_off[e] = s;
            s += (sh.rt.cnt[e] + BM - 1) / BM;
        }
        seg_off[E]  = sh.rt.base[E];
        tile_off[E] = s;
    }
}

// ---------------------------------------------------------------------------
// GEMM1 + SiLU (bf16 MFMA): act[p, 0:64@jb] = silu(x.w1g) * (x.w1u)
// Tile: 128 rows x 64 act-cols (=> gate 64 + up 64 B-cols), 4 waves 2x2.
// ---------------------------------------------------------------------------
__launch_bounds__(256, 2)
__global__ void gemm1_silu(const __hip_bfloat16* __restrict__ xb,
                           const __hip_bfloat16* __restrict__ w1t,   // [e][n=2816][k=1024]
                           const int* __restrict__ tok,
                           const int* __restrict__ seg_off,
                           const int* __restrict__ tile_off,
                           __hip_bfloat16* __restrict__ act)         // [p][1408]
{
    __shared__ __align__(16) __hip_bfloat16 As[BM * BK];    // [row][k] 8KB
    __shared__ __align__(16) __hip_bfloat16 Bg[BNA * BK];   // [col][k] 4KB
    __shared__ __align__(16) __hip_bfloat16 Bu[BNA * BK];   // 4KB
    __shared__ int tokS[BM];

    int bx = blockIdx.x;
    if (bx >= tile_off[E]) return;
    int e = 0;
#pragma unroll
    for (int i = 1; i < E; ++i) if (bx >= tile_off[i]) e = i;
    int row0 = seg_off[e] + (bx - tile_off[e]) * BM;
    int rend = seg_off[e + 1];
    int jb   = blockIdx.y * BNA;

    int tid = threadIdx.x;
    if (tid < BM) {
        int gr = row0 + tid;
        tokS[tid] = tok[gr < NP ? gr : NP - 1];
    }
    __syncthreads();

    // staging addresses: thread covers 16B; row = tid/4, byte-in-row = (tid&3)*16
    int arow = tid >> 2;
    int aoff = (tid & 3) * 16;
    const char* xB  = (const char*)xb;
    const char* w1B = (const char*)(w1t + (size_t)e * I2 * H);
    const char* srcA0 = xB + (size_t)tokS[arow]      * 2048 + aoff;   // rows 0..63
    const char* srcA1 = xB + (size_t)tokS[arow + 64] * 2048 + aoff;   // rows 64..127
    const char* srcG  = w1B + (size_t)(jb + arow)      * 2048 + aoff;
    const char* srcU  = w1B + (size_t)(II + jb + arow) * 2048 + aoff;
    __hip_bfloat16* dA0 = &As[tid * 8];
    __hip_bfloat16* dA1 = &As[2048 + tid * 8];
    __hip_bfloat16* dG  = &Bg[tid * 8];
    __hip_bfloat16* dU  = &Bu[tid * 8];

    int lane = tid & 63;
    int w  = tid >> 6;
    int wm = w >> 1, wn = w & 1;   // wave region: rows wm*64, act-cols wn*32
    int fr = lane & 15;            // fragment row/col
    int kc = lane >> 4;            // k-chunk (8 elems each)

    f32x4 accg[4][2] = {};
    f32x4 accu[4][2] = {};
    const short8v* Asv = (const short8v*)As;
    const short8v* Bgv = (const short8v*)Bg;
    const short8v* Buv = (const short8v*)Bu;

    for (int k0 = 0; k0 < H; k0 += BK) {
        gload16(dA0, srcA0);
        gload16(dA1, srcA1);
        gload16(dG, srcG);
        gload16(dU, srcU);
        srcA0 += 64; srcA1 += 64; srcG += 64; srcU += 64;
        __syncthreads();   // drains vmcnt before LDS reads

        short8v a[4], g[2], u[2];
#pragma unroll
        for (int m = 0; m < 4; ++m)
            a[m] = Asv[(wm * 64 + m * 16 + fr) * 4 + kc];
#pragma unroll
        for (int n = 0; n < 2; ++n) {
            g[n] = Bgv[(wn * 32 + n * 16 + fr) * 4 + kc];
            u[n] = Buv[(wn * 32 + n * 16 + fr) * 4 + kc];
        }
#pragma unroll
        for (int m = 0; m < 4; ++m)
#pragma unroll
            for (int n = 0; n < 2; ++n) {
                accg[m][n] = __builtin_amdgcn_mfma_f32_16x16x32_bf16(a[m], g[n], accg[m][n], 0, 0, 0);
                accu[m][n] = __builtin_amdgcn_mfma_f32_16x16x32_bf16(a[m], u[n], accu[m][n], 0, 0, 0);
            }
        __syncthreads();
    }

    // epilogue: silu(gate)*up -> bf16 act.  C/D layout: col=lane&15, row=(lane>>4)*4+j
#pragma unroll
    for (int m = 0; m < 4; ++m)
#pragma unroll
        for (int n = 0; n < 2; ++n) {
            int col = jb + wn * 32 + n * 16 + fr;
#pragma unroll
            for (int j = 0; j < 4; ++j) {
                int gr = row0 + wm * 64 + m * 16 + kc * 4 + j;
                if (gr < rend) {
                    float gg = accg[m][n][j];
                    float s  = gg / (1.0f + __expf(-gg));
                    act[(size_t)gr * II + col] = __float2bfloat16(s * accu[m][n][j]);
                }
            }
        }
}

// ---------------------------------------------------------------------------
// GEMM2: y[q] = act[q] . w2[e]   (plain stores, rows dense in sorted order)
// Tile: 128 rows x 128 cols, 4 waves 2x2, K=1408.
// ---------------------------------------------------------------------------
__launch_bounds__(256, 2)
__global__ void gemm2(const __hip_bfloat16* __restrict__ act,
                      const __hip_bfloat16* __restrict__ w2t,  // [e][n=1024][k=1408]
                      const int* __restrict__ seg_off,
                      const int* __restrict__ tile_off,
                      float* __restrict__ y)                   // [q][1024]
{
    __shared__ __align__(16) __hip_bfloat16 As[BM * BK];     // 8KB
    __shared__ __align__(16) __hip_bfloat16 Bs[BN2 * BK];    // 8KB

    int bx = blockIdx.x;
    if (bx >= tile_off[E]) return;
    int e = 0;
#pragma unroll
    for (int i = 1; i < E; ++i) if (bx >= tile_off[i]) e = i;
    int row0 = seg_off[e] + (bx - tile_off[e]) * BM;
    int rend = seg_off[e + 1];
    int nb   = blockIdx.y * BN2;

    int tid = threadIdx.x;
    int arow = tid >> 2;
    int aoff = (tid & 3) * 16;
    const char* actB = (const char*)act;
    const char* w2B  = (const char*)(w2t + (size_t)e * H * II);
    int r0c = row0 + arow;       r0c = r0c < NP ? r0c : NP - 1;
    int r1c = row0 + arow + 64;  r1c = r1c < NP ? r1c : NP - 1;
    const char* srcA0 = actB + (size_t)r0c * 2816 + aoff;
    const char* srcA1 = actB + (size_t)r1c * 2816 + aoff;
    const char* srcB0 = w2B + (size_t)(nb + arow)      * 2816 + aoff;
    const char* srcB1 = w2B + (size_t)(nb + arow + 64) * 2816 + aoff;
    __hip_bfloat16* dA0 = &As[tid * 8];
    __hip_bfloat16* dA1 = &As[2048 + tid * 8];
    __hip_bfloat16* dB0 = &Bs[tid * 8];
    __hip_bfloat16* dB1 = &Bs[2048 + tid * 8];

    int lane = tid & 63;
    int w  = tid >> 6;
    int wm = w >> 1, wn = w & 1;   // wave region: rows wm*64, cols wn*64
    int fr = lane & 15;
    int kc = lane >> 4;

    f32x4 acc[4][4] = {};
    const short8v* Asv = (const short8v*)As;
    const short8v* Bsv = (const short8v*)Bs;

    for (int k0 = 0; k0 < II; k0 += BK) {
        gload16(dA0, srcA0);
        gload16(dA1, srcA1);
        gload16(dB0, srcB0);
        gload16(dB1, srcB1);
        srcA0 += 64; srcA1 += 64; srcB0 += 64; srcB1 += 64;
        __syncthreads();

        short8v a[4], b[4];
#pragma unroll
        for (int m = 0; m < 4; ++m)
            a[m] = Asv[(wm * 64 + m * 16 + fr) * 4 + kc];
#pragma unroll
        for (int n = 0; n < 4; ++n)
            b[n] = Bsv[(wn * 64 + n * 16 + fr) * 4 + kc];
#pragma unroll
        for (int m = 0; m < 4; ++m)
#pragma unroll
            for (int n = 0; n < 4; ++n)
                acc[m][n] = __builtin_amdgcn_mfma_f32_16x16x32_bf16(a[m], b[n], acc[m][n], 0, 0, 0);
        __syncthreads();
    }

#pragma unroll
    for (int m = 0; m < 4; ++m)
#pragma unroll
        for (int n = 0; n < 4; ++n) {
            int col = nb + wn * 64 + n * 16 + fr;
#pragma unroll
            for (int j = 0; j < 4; ++j) {
                int lr = wm * 64 + m * 16 + kc * 4 + j;
                int gr = row0 + lr;
                if (gr < rend)
                    y[(size_t)gr * H + col] = acc[m][n][j];
            }
        }
}

// ---------------------------------------------------------------------------
// gather: out[t] = rw[t,0] * y[inv[2t]] + rw[t,1] * y[inv[2t+1]]
// ---------------------------------------------------------------------------
__global__ void gather_out(const float* __restrict__ y, const int* __restrict__ inv,
                           const float* __restrict__ rw, float* __restrict__ out)
{
    int gid = blockIdx.x * 256 + threadIdx.x;     // 524288 threads, float4 each
    int t = gid >> 8;                              // 256 float4 groups per token
    int c = (gid & 255) * 4;
    int q0 = inv[2 * t], q1 = inv[2 * t + 1];
    float w0 = rw[2 * t], w1 = rw[2 * t + 1];
    float4 a = *(const float4*)(y + (size_t)q0 * H + c);
    float4 b = *(const float4*)(y + (size_t)q1 * H + c);
    float4 o;
    o.x = w0 * a.x + w1 * b.x;
    o.y = w0 * a.y + w1 * b.y;
    o.z = w0 * a.z + w1 * b.z;
    o.w = w0 * a.w + w1 * b.w;
    *(float4*)(out + (size_t)t * H + c) = o;
}

// ---------------------------------------------------------------------------
extern "C" void kernel_launch(void* const* d_in, const int* in_sizes, int n_in,
                              void* d_out, int out_size, void* d_ws, size_t ws_size,
                              hipStream_t stream)
{
    const float* x   = (const float*)d_in[0];
    const int*   ids = (const int*)d_in[1];
    const float* rw  = (const float*)d_in[2];
    const float* w1  = (const float*)d_in[3];
    const float* w2  = (const float*)d_in[4];
    float*       out = (float*)d_out;

    char* ws = (char*)d_ws;
    int*   tok  = (int*)ws;                              // 16 KB
    int*   inv  = (int*)(ws + 16384);                    // 16 KB
    int*   seg  = (int*)(ws + 32768);                    // E+1
    int*   tile = (int*)(ws + 32768 + 64);               // E+1
    __hip_bfloat16* xb  = (__hip_bfloat16*)(ws + 65536);                    // 4 MB
    __hip_bfloat16* w1t = (__hip_bfloat16*)(ws + 4259840);                  // 46.1 MB
    __hip_bfloat16* w2t = (__hip_bfloat16*)(ws + 50397184);                 // 23.1 MB
    __hip_bfloat16* act = (__hip_bfloat16*)(ws + 73465856);                 // 11.5 MB
    float*          y   = (float*)(ws + 85000192);                          // 16 MB

    prep_kernel<<<PREP_BLKS, 256, 0, stream>>>(x, w1, w2, ids, xb, w1t, w2t,
                                               tok, inv, seg, tile);

    gemm1_silu<<<dim3(GX, II / BNA), 256, 0, stream>>>(xb, w1t, tok, seg, tile, act);  // (40,22)
    gemm2<<<dim3(GX, H / BN2), 256, 0, stream>>>(act, w2t, seg, tile, y);              // (40,8)
    gather_out<<<(T * H) / (256 * 4), 256, 0, stream>>>(y, inv, rw, out);              // 2048 blocks
}